// Round 3
// baseline (90.041 us; speedup 1.0000x reference)
//
#include <hip/hip_runtime.h>

#define BLOCK 256
#define EPSF 1e-8f

// Single fused kernel: per-box L1 + rotated-BEV GIoU, block partials, and a
// last-block-done final reduction (deterministic: fixed summation order,
// counter reset by hipMemsetAsync each launch).
__global__ __launch_bounds__(BLOCK) void box_loss_fused(
    const float* __restrict__ box, const float* __restrict__ tgt,
    const float* __restrict__ wgt, int n, int nblk,
    float* partials, unsigned int* counter,
    const int* __restrict__ avg_factor, float* __restrict__ out)
{
    // 32 KB arena, aliased phases:
    //   staging: floats [0..5632)  (box slab [0..2816), tgt slab [2816..5632))
    //   clip:    Ax[0..2048) Ay[2048..4096) Bx[4096..6144) By[6144..8192)
    //   reduce:  red[0..8), flag at [16]  (clip buffers dead by then)
    __shared__ __align__(16) float smem[8192];
    float* stage = smem;
    float* Ax = smem;
    float* Ay = smem + 2048;
    float* Bx = smem + 4096;
    float* By = smem + 6144;
    float* red = smem;
    int*   flag = (int*)(smem + 16);

    const int tid  = threadIdx.x;
    const int bid  = blockIdx.x;
    const int slab = bid * BLOCK;
    const int slabN = min(BLOCK, n - slab);
    const size_t g0 = (size_t)slab * 11;

    // ---- phase 1: coalesced float4 staging + on-the-fly L1 ----
    float l1sum = 0.f;
    if (slabN == BLOCK) {
        const float4* b4 = (const float4*)(box + g0);
        const float4* t4 = (const float4*)(tgt + g0);
        const float4* w4 = (const float4*)(wgt + g0);
        float4* sb4 = (float4*)stage;            // 704 float4
        float4* st4 = (float4*)(stage + 2816);
#pragma unroll
        for (int k = 0; k < 3; ++k) {
            int idx = tid + k * BLOCK;
            if (idx < 704) {
                float4 vb = b4[idx], vt = t4[idx], vw = w4[idx];
                l1sum += fabsf(vb.x - vt.x) * vw.x + fabsf(vb.y - vt.y) * vw.y
                       + fabsf(vb.z - vt.z) * vw.z + fabsf(vb.w - vt.w) * vw.w;
                sb4[idx] = vb;
                st4[idx] = vt;
            }
        }
    } else {
        const int F = slabN * 11;
        for (int j = tid; j < F; j += BLOCK) {
            float bb = box[g0 + j], tt = tgt[g0 + j], ww = wgt[g0 + j];
            l1sum += fabsf(bb - tt) * ww;
            stage[j] = bb; stage[2816 + j] = tt;
        }
    }
    __syncthreads();

    // ---- pull this thread's params ----
    float cx1 = 0, cy1 = 0, lw1 = 0, ll1 = 0, sy1 = 0, cw1 = 0;
    float cx2 = 0, cy2 = 0, lw2 = 0, ll2 = 0, sy2 = 0, cw2 = 0;
    const bool active = (tid < slabN);
    if (active) {
        const int b = tid * 11;
        cx1 = stage[b + 0]; cy1 = stage[b + 1];
        lw1 = stage[b + 3]; ll1 = stage[b + 4];
        sy1 = stage[b + 6]; cw1 = stage[b + 7];
        const int t = 2816 + b;
        cx2 = stage[t + 0]; cy2 = stage[t + 1];
        lw2 = stage[t + 3]; ll2 = stage[t + 4];
        sy2 = stage[t + 6]; cw2 = stage[t + 7];
    }
    __syncthreads();   // staging dead; arena becomes clip buffers

    float giou_term = 0.f;
    float w1 = 0.f, l1 = 0.f;
    if (active) {
        // decode: sin(atan2(s,c)) = s*rsqrt(s^2+c^2); exp via HW
        w1 = __expf(lw1); l1 = __expf(ll1);
        float w2 = __expf(lw2), l2 = __expf(ll2);
        float r1 = rsqrtf(fmaxf(sy1 * sy1 + cw1 * cw1, 1e-30f));
        float s1 = sy1 * r1, c1 = cw1 * r1;
        float r2 = rsqrtf(fmaxf(sy2 * sy2 + cw2 * cw2, 1e-30f));
        float s2 = sy2 * r2, c2 = cw2 * r2;

        float hx1 = 0.5f * w1, hy1 = 0.5f * l1;
        float hx2 = 0.5f * w2, hy2 = 0.5f * l2;

        const float LX[4] = { -1.f, 1.f, 1.f, -1.f };
        const float LY[4] = { -1.f, -1.f, 1.f, 1.f };
        float v1x[4], v1y[4], v2x[4], v2y[4];
#pragma unroll
        for (int k = 0; k < 4; ++k) {
            float lx = LX[k] * hx1, ly = LY[k] * hy1;
            v1x[k] = lx * c1 - ly * s1 + cx1;
            v1y[k] = lx * s1 + ly * c1 + cy1;
            float mx = LX[k] * hx2, my = LY[k] * hy2;
            v2x[k] = mx * c2 - my * s2 + cx2;
            v2y[k] = mx * s2 + my * c2 + cy2;
        }

        // enclosing AABB over 8 original vertices
        float minx = v1x[0], maxx = v1x[0], miny = v1y[0], maxy = v1y[0];
#pragma unroll
        for (int k = 1; k < 4; ++k) {
            minx = fminf(minx, v1x[k]); maxx = fmaxf(maxx, v1x[k]);
            miny = fminf(miny, v1y[k]); maxy = fmaxf(maxy, v1y[k]);
        }
#pragma unroll
        for (int k = 0; k < 4; ++k) {
            minx = fminf(minx, v2x[k]); maxx = fmaxf(maxx, v2x[k]);
            miny = fminf(miny, v2y[k]); maxy = fmaxf(maxy, v2y[k]);
        }
        float enc = (maxx - minx) * (maxy - miny);

        // ---- Sutherland-Hodgman with s-value algebra ----
        // side(p) = dx*p.y - dy*p.x + c0 ; num = s_prev ; den = s_prev - s_cur + EPS
        int cnt;
        {   // pass 0: registers -> A (edge v2[0]->v2[1]); max 8 emits, no cap needed
            float ax = v2x[0], ay = v2y[0];
            float dx = v2x[1] - ax, dy = v2y[1] - ay;
            float c0 = dy * ax - dx * ay;
            int m = 0;
            float pvx = v1x[3], pvy = v1y[3];
            float sp = dx * pvy - dy * pvx + c0;
#pragma unroll
            for (int ii = 0; ii < 4; ++ii) {
                float cvx = v1x[ii], cvy = v1y[ii];
                float sc = dx * cvy - dy * cvx + c0;
                bool pin = sp >= 0.f, cin = sc >= 0.f;
                if (pin != cin) {
                    float t = __fdividef(sp, sp - sc + EPSF);
                    Ax[m * BLOCK + tid] = fmaf(t, cvx - pvx, pvx);
                    Ay[m * BLOCK + tid] = fmaf(t, cvy - pvy, pvy);
                    ++m;
                }
                if (cin) { Ax[m * BLOCK + tid] = cvx; Ay[m * BLOCK + tid] = cvy; ++m; }
                pvx = cvx; pvy = cvy; sp = sc;
            }
            cnt = (m < 3) ? 0 : m;
        }

        auto clip_pass = [&](const float* sxp, const float* syp, int scnt,
                             float* dxp, float* dyp,
                             float ax, float ay, float bx2, float by2) -> int {
            float dx = bx2 - ax, dy = by2 - ay;
            float c0 = dy * ax - dx * ay;
            int m = 0;
            float pvx = sxp[(scnt - 1) * BLOCK + tid];
            float pvy = syp[(scnt - 1) * BLOCK + tid];
            float sp = dx * pvy - dy * pvx + c0;
            for (int ii = 0; ii < scnt; ++ii) {
                float cvx = sxp[ii * BLOCK + tid];
                float cvy = syp[ii * BLOCK + tid];
                float sc = dx * cvy - dy * cvx + c0;
                bool pin = sp >= 0.f, cin = sc >= 0.f;
                if ((pin != cin) && m < 8) {
                    float t = __fdividef(sp, sp - sc + EPSF);
                    dxp[m * BLOCK + tid] = fmaf(t, cvx - pvx, pvx);
                    dyp[m * BLOCK + tid] = fmaf(t, cvy - pvy, pvy);
                    ++m;
                }
                if (cin && m < 8) {
                    dxp[m * BLOCK + tid] = cvx; dyp[m * BLOCK + tid] = cvy; ++m;
                }
                pvx = cvx; pvy = cvy; sp = sc;
            }
            return (m < 3) ? 0 : m;
        };

        if (cnt) cnt = clip_pass(Ax, Ay, cnt, Bx, By,
                                 v2x[1], v2y[1], v2x[2], v2y[2]);
        if (cnt) cnt = clip_pass(Bx, By, cnt, Ax, Ay,
                                 v2x[2], v2y[2], v2x[3], v2y[3]);

        // pass 3: A -> streaming shoelace (edge v2[3]->v2[0])
        float inter = 0.f;
        if (cnt) {
            float ax = v2x[3], ay = v2y[3];
            float dx = v2x[0] - ax, dy = v2y[0] - ay;
            float c0 = dy * ax - dx * ay;
            int m = 0;
            float fx = 0.f, fy = 0.f, lx = 0.f, ly = 0.f, acc = 0.f;
            float pvx = Ax[(cnt - 1) * BLOCK + tid];
            float pvy = Ay[(cnt - 1) * BLOCK + tid];
            float sp = dx * pvy - dy * pvx + c0;
            for (int ii = 0; ii < cnt; ++ii) {
                float cvx = Ax[ii * BLOCK + tid];
                float cvy = Ay[ii * BLOCK + tid];
                float sc = dx * cvy - dy * cvx + c0;
                bool pin = sp >= 0.f, cin = sc >= 0.f;
                if ((pin != cin) && m < 8) {
                    float t = __fdividef(sp, sp - sc + EPSF);
                    float px = fmaf(t, cvx - pvx, pvx);
                    float py = fmaf(t, cvy - pvy, pvy);
                    if (m == 0) { fx = px; fy = py; }
                    else        { acc += lx * py - ly * px; }
                    lx = px; ly = py; ++m;
                }
                if (cin && m < 8) {
                    if (m == 0) { fx = cvx; fy = cvy; }
                    else        { acc += lx * cvy - ly * cvx; }
                    lx = cvx; ly = cvy; ++m;
                }
                pvx = cvx; pvy = cvy; sp = sc;
            }
            if (m >= 3) inter = fabsf(acc + lx * fy - ly * fx) * 0.5f;
        }

        float areaU = w1 * l1 + __expf(lw2) * __expf(ll2) - inter;
        float iou = inter / (areaU + EPSF);
        float giou = iou - (enc - areaU) / (enc + EPSF);
        giou_term = 1.f - giou;
    }

    // ---- block reduction (wave=64) ----
    float sb = l1sum, sg = giou_term;
#pragma unroll
    for (int off = 32; off > 0; off >>= 1) {
        sb += __shfl_down(sb, off);
        sg += __shfl_down(sg, off);
    }
    const int wave = tid >> 6, lane = tid & 63;
    __syncthreads();                    // clip buffers dead; arena -> red/flag
    if (lane == 0) { red[wave] = sb; red[4 + wave] = sg; }
    __syncthreads();
    if (tid == 0) {
        float a = red[0] + red[1] + red[2] + red[3];
        float g = red[4] + red[5] + red[6] + red[7];
        partials[2 * (size_t)bid]     = a;
        partials[2 * (size_t)bid + 1] = g;
        __threadfence();
        unsigned tkt = __hip_atomic_fetch_add(counter, 1u, __ATOMIC_ACQ_REL,
                                              __HIP_MEMORY_SCOPE_AGENT);
        *flag = (tkt == (unsigned)(nblk - 1)) ? 1 : 0;
    }
    __syncthreads();
    const bool last = (*flag != 0);

    // ---- last block: deterministic final reduction ----
    if (last) {
        float a = 0.f, g = 0.f;
        for (int i = tid; i < nblk; i += BLOCK) {
            a += __hip_atomic_load(&partials[2 * (size_t)i],
                                   __ATOMIC_RELAXED, __HIP_MEMORY_SCOPE_AGENT);
            g += __hip_atomic_load(&partials[2 * (size_t)i + 1],
                                   __ATOMIC_RELAXED, __HIP_MEMORY_SCOPE_AGENT);
        }
#pragma unroll
        for (int off = 32; off > 0; off >>= 1) {
            a += __shfl_down(a, off);
            g += __shfl_down(g, off);
        }
        if (lane == 0) { red[wave] = a; red[4 + wave] = g; }
    }
    __syncthreads();
    if (last && tid == 0) {
        float af = (float)(*avg_factor);
        if (af < 1.f) af = 1.f;
        float sa = red[0] + red[1] + red[2] + red[3];
        float sg2 = red[4] + red[5] + red[6] + red[7];
        out[0] = sa / af;
        out[1] = sg2 / af;
    }
}

extern "C" void kernel_launch(void* const* d_in, const int* in_sizes, int n_in,
                              void* d_out, int out_size, void* d_ws, size_t ws_size,
                              hipStream_t stream) {
    const float* box = (const float*)d_in[0];
    const float* tgt = (const float*)d_in[1];
    const float* wgt = (const float*)d_in[2];
    const int*   af  = (const int*)d_in[3];
    float* out = (float*)d_out;

    int n = in_sizes[0] / 11;                 // number of boxes
    int nblk = (n + BLOCK - 1) / BLOCK;       // one box per thread
    if (nblk < 1) nblk = 1;

    float* partials = (float*)d_ws;
    size_t cnt_off = ((size_t)nblk * 2 * sizeof(float) + 255) & ~(size_t)255;
    unsigned int* counter = (unsigned int*)((char*)d_ws + cnt_off);

    hipMemsetAsync(counter, 0, sizeof(unsigned int), stream);
    hipLaunchKernelGGL(box_loss_fused, dim3(nblk), dim3(BLOCK), 0, stream,
                       box, tgt, wgt, n, nblk, partials, counter, af, out);
}

// Round 4
// 44.358 us; speedup vs baseline: 2.0299x; 2.0299x over previous
//
#include <hip/hip_runtime.h>

#define BLOCK 256
#define EPSF 1e-8f

// Streaming Sutherland-Hodgman clip stage state (all in registers).
struct ClipState {
    float fx, fy, fs;   // first valid point of this stage's input ring + its side
    float lx, ly, ls;   // last valid point + side
    bool  has;          // any valid point seen
};

// Process one candidate point (px,py,valid pv) through a clip stage whose
// side value at this point is s (inside = s>=0). Emits up to 2 candidates
// (crossing then vertex) to the next stage via `emit`. Straight-line,
// fully predicated — no branches, no memory.
template <typename F>
__device__ __forceinline__ void stage_point(ClipState& st, float s,
                                            float px, float py, bool pv, F&& emit) {
    bool in  = s >= 0.f;
    bool cr  = pv && st.has && (in != (st.ls >= 0.f));
    float t  = __fdividef(st.ls, st.ls - s + EPSF);
    emit(fmaf(t, px - st.lx, st.lx), fmaf(t, py - st.ly, st.ly), cr);
    emit(px, py, pv && in);
    bool neu = pv && !st.has;
    st.fx = neu ? px : st.fx;  st.fy = neu ? py : st.fy;  st.fs = neu ? s : st.fs;
    st.lx = pv  ? px : st.lx;  st.ly = pv  ? py : st.ly;  st.ls = pv  ? s : st.ls;
    st.has = st.has || pv;
}

// Close the ring: process the wrap edge (last -> first).
template <typename F>
__device__ __forceinline__ void stage_wrap(ClipState& st, F&& emit) {
    bool in = st.fs >= 0.f;
    bool cr = st.has && (in != (st.ls >= 0.f));
    float t = __fdividef(st.ls, st.ls - st.fs + EPSF);
    emit(fmaf(t, st.fx - st.lx, st.lx), fmaf(t, st.fy - st.ly, st.ly), cr);
    emit(st.fx, st.fy, st.has && in);
}

__global__ __launch_bounds__(BLOCK) void box_loss_main(
    const float* __restrict__ box, const float* __restrict__ tgt,
    const float* __restrict__ wgt, int n, float* __restrict__ partials)
{
    __shared__ __align__(16) float stage[5632];   // box slab [0,2816) | tgt slab [2816,5632)
    __shared__ float red[8];

    const int tid  = threadIdx.x;
    const int slab = blockIdx.x * BLOCK;
    const int slabN = min(BLOCK, n - slab);
    const size_t g0 = (size_t)slab * 11;

    // ---- coalesced float4 staging + on-the-fly L1 (weight is never stored) ----
    float l1sum = 0.f;
    if (slabN == BLOCK) {
        const float4* b4 = (const float4*)(box + g0);
        const float4* t4 = (const float4*)(tgt + g0);
        const float4* w4 = (const float4*)(wgt + g0);
        float4* sb4 = (float4*)stage;
        float4* st4 = (float4*)(stage + 2816);
#pragma unroll
        for (int k = 0; k < 3; ++k) {
            int idx = tid + k * BLOCK;
            if (idx < 704) {
                float4 vb = b4[idx], vt = t4[idx], vw = w4[idx];
                l1sum += fabsf(vb.x - vt.x) * vw.x + fabsf(vb.y - vt.y) * vw.y
                       + fabsf(vb.z - vt.z) * vw.z + fabsf(vb.w - vt.w) * vw.w;
                sb4[idx] = vb;
                st4[idx] = vt;
            }
        }
    } else {
        const int F = slabN * 11;
        for (int j = tid; j < F; j += BLOCK) {
            float bb = box[g0 + j], tt = tgt[g0 + j], ww = wgt[g0 + j];
            l1sum += fabsf(bb - tt) * ww;
            stage[j] = bb; stage[2816 + j] = tt;
        }
    }
    __syncthreads();

    float giou_term = 0.f;
    if (tid < slabN) {
        const int b = tid * 11, t = 2816 + b;
        float cx1 = stage[b + 0], cy1 = stage[b + 1];
        float lw1 = stage[b + 3], ll1 = stage[b + 4];
        float sy1 = stage[b + 6], cw1 = stage[b + 7];
        float cx2 = stage[t + 0], cy2 = stage[t + 1];
        float lw2 = stage[t + 3], ll2 = stage[t + 4];
        float sy2 = stage[t + 6], cw2 = stage[t + 7];

        // decode: sin(atan2(s,c)) = s*rsqrt(s^2+c^2); exp via HW
        float w1 = __expf(lw1), l1v = __expf(ll1);
        float w2 = __expf(lw2), l2v = __expf(ll2);
        float r1 = rsqrtf(fmaxf(sy1 * sy1 + cw1 * cw1, 1e-30f));
        float s1 = sy1 * r1, c1 = cw1 * r1;
        float r2 = rsqrtf(fmaxf(sy2 * sy2 + cw2 * cw2, 1e-30f));
        float s2 = sy2 * r2, c2 = cw2 * r2;

        float hx1 = 0.5f * w1, hy1 = 0.5f * l1v;
        float hx2 = 0.5f * w2, hy2 = 0.5f * l2v;

        // enclosing AABB (world frame), closed form == max over corners
        float e1x = fabsf(hx1 * c1) + fabsf(hy1 * s1);
        float e1y = fabsf(hx1 * s1) + fabsf(hy1 * c1);
        float e2x = fabsf(hx2 * c2) + fabsf(hy2 * s2);
        float e2y = fabsf(hx2 * s2) + fabsf(hy2 * c2);
        float enc = (fmaxf(cx1 + e1x, cx2 + e2x) - fminf(cx1 - e1x, cx2 - e2x))
                  * (fmaxf(cy1 + e1y, cy2 + e2y) - fminf(cy1 - e1y, cy2 - e2y));

        // rect1 corners in rect2's local frame (rect2 becomes axis-aligned box)
        float dxw = cx1 - cx2, dyw = cy1 - cy2;
        float txl =  c2 * dxw + s2 * dyw;
        float tyl = -s2 * dxw + c2 * dyw;
        float cr_ = c1 * c2 + s1 * s2;   // cos(yaw1 - yaw2)
        float sr_ = s1 * c2 - c1 * s2;   // sin(yaw1 - yaw2)
        const float UX[4] = { -1.f, 1.f, 1.f, -1.f };
        const float UY[4] = { -1.f, -1.f, 1.f, 1.f };
        float qx[4], qy[4];
#pragma unroll
        for (int k = 0; k < 4; ++k) {
            float ux = UX[k] * hx1, uy = UY[k] * hy1;
            qx[k] = txl + ux * cr_ - uy * sr_;
            qy[k] = tyl + ux * sr_ + uy * cr_;
        }

        // ---- streaming clip cascade (clip0 static, then A,B,C, then shoelace)
        // clip0: y >= -hy2 ; A: x <= hx2 ; B: y <= hy2 ; C: x >= -hx2
        ClipState A = {0,0,0,0,0,0,false};
        ClipState B = {0,0,0,0,0,0,false};
        ClipState C = {0,0,0,0,0,0,false};
        float shfx = 0.f, shfy = 0.f, shlx = 0.f, shly = 0.f, shacc = 0.f;
        bool  shhas = false;

        auto shoe = [&](float px, float py, bool pv) {
            float c = shlx * py - shly * px;
            shacc += (pv && shhas) ? c : 0.f;
            bool neu = pv && !shhas;
            shfx = neu ? px : shfx;  shfy = neu ? py : shfy;
            shlx = pv  ? px : shlx;  shly = pv  ? py : shly;
            shhas = shhas || pv;
        };
        auto emitC = [&](float px, float py, bool pv) {
            stage_point(C, px + hx2, px, py, pv, shoe);
        };
        auto emitB = [&](float px, float py, bool pv) {
            stage_point(B, hy2 - py, px, py, pv, emitC);
        };
        auto emitA = [&](float px, float py, bool pv) {
            stage_point(A, hx2 - px, px, py, pv, emitB);
        };

        // clip0 over the static 4-corner ring (all valid): emit [ip_k, cur_k]
        {
            float s0[4];
#pragma unroll
            for (int k = 0; k < 4; ++k) s0[k] = qy[k] + hy2;
            int prev = 3;
#pragma unroll
            for (int k = 0; k < 4; ++k) {
                bool pin = s0[prev] >= 0.f, cin = s0[k] >= 0.f;
                float tt = __fdividef(s0[prev], s0[prev] - s0[k] + EPSF);
                emitA(fmaf(tt, qx[k] - qx[prev], qx[prev]),
                      fmaf(tt, qy[k] - qy[prev], qy[prev]), pin != cin);
                emitA(qx[k], qy[k], cin);
                prev = k;
            }
        }
        stage_wrap(A, emitB);
        stage_wrap(B, emitC);
        stage_wrap(C, shoe);
        // close shoelace ring
        float cw = shlx * shfy - shly * shfx;
        shacc += shhas ? cw : 0.f;
        float inter = 0.5f * fabsf(shacc);

        float areaU = w1 * l1v + w2 * l2v - inter;
        float iou = inter / (areaU + EPSF);
        float giou = iou - (enc - areaU) / (enc + EPSF);
        giou_term = 1.f - giou;
    }

    // ---- block reduction (wave=64) ----
    float sb = l1sum, sg = giou_term;
#pragma unroll
    for (int off = 32; off > 0; off >>= 1) {
        sb += __shfl_down(sb, off);
        sg += __shfl_down(sg, off);
    }
    const int wave = tid >> 6, lane = tid & 63;
    if (lane == 0) { red[wave] = sb; red[4 + wave] = sg; }
    __syncthreads();
    if (tid == 0) {
        float a = red[0] + red[1] + red[2] + red[3];
        float g = red[4] + red[5] + red[6] + red[7];
        partials[2 * (size_t)blockIdx.x]     = a;
        partials[2 * (size_t)blockIdx.x + 1] = g;
    }
}

// Deterministic final reduction of per-block partials + 1/af scaling.
__global__ __launch_bounds__(256) void box_loss_final(
    const float* __restrict__ partials, int nblk,
    const int* __restrict__ avg_factor, float* __restrict__ out)
{
    __shared__ float red[8];
    float a = 0.f, g = 0.f;
    for (int i = threadIdx.x; i < nblk; i += 256) {
        a += partials[2 * (size_t)i];
        g += partials[2 * (size_t)i + 1];
    }
#pragma unroll
    for (int off = 32; off > 0; off >>= 1) {
        a += __shfl_down(a, off);
        g += __shfl_down(g, off);
    }
    const int wave = threadIdx.x >> 6, lane = threadIdx.x & 63;
    if (lane == 0) { red[wave] = a; red[4 + wave] = g; }
    __syncthreads();
    if (threadIdx.x == 0) {
        float af = (float)(*avg_factor);
        if (af < 1.f) af = 1.f;
        out[0] = (red[0] + red[1] + red[2] + red[3]) / af;
        out[1] = (red[4] + red[5] + red[6] + red[7]) / af;
    }
}

extern "C" void kernel_launch(void* const* d_in, const int* in_sizes, int n_in,
                              void* d_out, int out_size, void* d_ws, size_t ws_size,
                              hipStream_t stream) {
    const float* box = (const float*)d_in[0];
    const float* tgt = (const float*)d_in[1];
    const float* wgt = (const float*)d_in[2];
    const int*   af  = (const int*)d_in[3];
    float* out = (float*)d_out;
    float* partials = (float*)d_ws;

    int n = in_sizes[0] / 11;
    int nblk = (n + BLOCK - 1) / BLOCK;
    if (nblk < 1) nblk = 1;

    hipLaunchKernelGGL(box_loss_main, dim3(nblk), dim3(BLOCK), 0, stream,
                       box, tgt, wgt, n, partials);
    hipLaunchKernelGGL(box_loss_final, dim3(1), dim3(256), 0, stream,
                       partials, nblk, af, out);
}

// Round 5
// 23.806 us; speedup vs baseline: 3.7823x; 1.8633x over previous
//
#include <hip/hip_runtime.h>

#define BLOCK 256
#define EPSF 1e-8f

// Branch-free Liang-Barsky: clip segment p + t*(d), t in [0,1], against
// |x| <= hx, |y| <= hy. Returns (tmin, tmax); empty iff tmax <= tmin.
__device__ __forceinline__ void lb_clip(float px, float py, float dx, float dy,
                                        float hx, float hy,
                                        float& tmin, float& tmax) {
    float sdx = (fabsf(dx) > 1e-30f) ? dx : copysignf(1e-30f, dx);
    float sdy = (fabsf(dy) > 1e-30f) ? dy : copysignf(1e-30f, dy);
    float rdx = __frcp_rn(sdx);
    float rdy = __frcp_rn(sdy);
    float t1x = (-hx - px) * rdx, t2x = (hx - px) * rdx;
    float t1y = (-hy - py) * rdy, t2y = (hy - py) * rdy;
    tmin = fmaxf(fmaxf(fminf(t1x, t2x), fminf(t1y, t2y)), 0.f);
    tmax = fminf(fminf(fmaxf(t1x, t2x), fmaxf(t1y, t2y)), 1.f);
}

__global__ __launch_bounds__(BLOCK) void box_loss_main(
    const float* __restrict__ box, const float* __restrict__ tgt,
    const float* __restrict__ wgt, int n, float* __restrict__ partials)
{
    __shared__ __align__(16) float stage[5632];   // box slab [0,2816) | tgt slab [2816,5632)
    __shared__ float red[8];

    const int tid  = threadIdx.x;
    const int slab = blockIdx.x * BLOCK;
    const int slabN = min(BLOCK, n - slab);
    const size_t g0 = (size_t)slab * 11;

    // ---- coalesced float4 staging + on-the-fly L1 (weight never stored) ----
    float l1sum = 0.f;
    if (slabN == BLOCK) {
        const float4* b4 = (const float4*)(box + g0);
        const float4* t4 = (const float4*)(tgt + g0);
        const float4* w4 = (const float4*)(wgt + g0);
        float4* sb4 = (float4*)stage;
        float4* st4 = (float4*)(stage + 2816);
#pragma unroll
        for (int k = 0; k < 3; ++k) {
            int idx = tid + k * BLOCK;
            if (idx < 704) {
                float4 vb = b4[idx], vt = t4[idx], vw = w4[idx];
                l1sum += fabsf(vb.x - vt.x) * vw.x + fabsf(vb.y - vt.y) * vw.y
                       + fabsf(vb.z - vt.z) * vw.z + fabsf(vb.w - vt.w) * vw.w;
                sb4[idx] = vb;
                st4[idx] = vt;
            }
        }
    } else {
        const int F = slabN * 11;
        for (int j = tid; j < F; j += BLOCK) {
            float bb = box[g0 + j], tt = tgt[g0 + j], ww = wgt[g0 + j];
            l1sum += fabsf(bb - tt) * ww;
            stage[j] = bb; stage[2816 + j] = tt;
        }
    }
    __syncthreads();

    float giou_term = 0.f;
    if (tid < slabN) {
        const int b = tid * 11, t = 2816 + b;
        float cx1 = stage[b + 0], cy1 = stage[b + 1];
        float lw1 = stage[b + 3], ll1 = stage[b + 4];
        float sy1 = stage[b + 6], cw1 = stage[b + 7];
        float cx2 = stage[t + 0], cy2 = stage[t + 1];
        float lw2 = stage[t + 3], ll2 = stage[t + 4];
        float sy2 = stage[t + 6], cw2 = stage[t + 7];

        // decode: sin(atan2(s,c)) = s*rsqrt(s^2+c^2); exp via HW
        float w1 = __expf(lw1), l1v = __expf(ll1);
        float w2 = __expf(lw2), l2v = __expf(ll2);
        float r1 = rsqrtf(fmaxf(sy1 * sy1 + cw1 * cw1, 1e-30f));
        float s1 = sy1 * r1, c1 = cw1 * r1;
        float r2 = rsqrtf(fmaxf(sy2 * sy2 + cw2 * cw2, 1e-30f));
        float s2 = sy2 * r2, c2 = cw2 * r2;

        float hx1 = 0.5f * w1, hy1 = 0.5f * l1v;
        float hx2 = 0.5f * w2, hy2 = 0.5f * l2v;

        // enclosing AABB (world frame), closed form == max/min over corners
        float e1x = fabsf(hx1 * c1) + fabsf(hy1 * s1);
        float e1y = fabsf(hx1 * s1) + fabsf(hy1 * c1);
        float e2x = fabsf(hx2 * c2) + fabsf(hy2 * s2);
        float e2y = fabsf(hx2 * s2) + fabsf(hy2 * c2);
        float enc = (fmaxf(cx1 + e1x, cx2 + e2x) - fminf(cx1 - e1x, cx2 - e2x))
                  * (fmaxf(cy1 + e1y, cy2 + e2y) - fminf(cy1 - e1y, cy2 - e2y));

        // rect1 pose in rect2's local frame (rect2 axis-aligned there)
        float dxw = cx1 - cx2, dyw = cy1 - cy2;
        float txl =  c2 * dxw + s2 * dyw;        // rect1 center in rect2 frame
        float tyl = -s2 * dxw + c2 * dyw;
        float cr_ = c1 * c2 + s1 * s2;           // cos(yaw1 - yaw2)
        float sr_ = s1 * c2 - c1 * s2;           // sin(yaw1 - yaw2)

        // rect1 corners in rect2 frame, CCW
        const float UX[4] = { -1.f, 1.f, 1.f, -1.f };
        const float UY[4] = { -1.f, -1.f, 1.f, 1.f };
        float qx[4], qy[4];
#pragma unroll
        for (int k = 0; k < 4; ++k) {
            float ux = UX[k] * hx1, uy = UY[k] * hy1;
            qx[k] = txl + ux * cr_ - uy * sr_;
            qy[k] = tyl + ux * sr_ + uy * cr_;
        }

        // ---- Green's theorem intersection area: 2*Area = sum of cross(a,b)
        // over boundary segments (rect1 edges inside rect2 + rect2 edges
        // inside rect1), all evaluated in rect2's frame.
        float inter2 = 0.f;

        // Part 1: rect1 edges clipped to |x|<=hx2, |y|<=hy2
#pragma unroll
        for (int k = 0; k < 4; ++k) {
            int kn = (k + 1) & 3;
            float px = qx[k], py = qy[k];
            float dx = qx[kn] - px, dy = qy[kn] - py;
            float t0, t1;
            lb_clip(px, py, dx, dy, hx2, hy2, t0, t1);
            float ax = fmaf(t0, dx, px), ay = fmaf(t0, dy, py);
            float bx = fmaf(t1, dx, px), by = fmaf(t1, dy, py);
            float c = ax * by - ay * bx;
            inter2 += (t1 > t0) ? c : 0.f;
        }

        // Part 2: rect2 edges (corners CCW in rect2 frame) clipped against
        // rect1; t-interval computed in rect1's local coords (t invariant).
        {
            float Rx[4] = { -hx2, hx2, hx2, -hx2 };
            float Ry[4] = { -hy2, -hy2, hy2, hy2 };
            float ux[4], uy[4];
#pragma unroll
            for (int k = 0; k < 4; ++k) {
                float zx = Rx[k] - txl, zy = Ry[k] - tyl;
                ux[k] =  cr_ * zx + sr_ * zy;    // into rect1 local
                uy[k] = -sr_ * zx + cr_ * zy;
            }
#pragma unroll
            for (int k = 0; k < 4; ++k) {
                int kn = (k + 1) & 3;
                float du = ux[kn] - ux[k], dv = uy[kn] - uy[k];
                float t0, t1;
                lb_clip(ux[k], uy[k], du, dv, hx1, hy1, t0, t1);
                float dzx = Rx[kn] - Rx[k], dzy = Ry[kn] - Ry[k];
                float ax = fmaf(t0, dzx, Rx[k]), ay = fmaf(t0, dzy, Ry[k]);
                float bx = fmaf(t1, dzx, Rx[k]), by = fmaf(t1, dzy, Ry[k]);
                float c = ax * by - ay * bx;
                inter2 += (t1 > t0) ? c : 0.f;
            }
        }

        float inter = 0.5f * fabsf(inter2);

        float areaU = w1 * l1v + w2 * l2v - inter;
        float iou = inter / (areaU + EPSF);
        float giou = iou - (enc - areaU) / (enc + EPSF);
        giou_term = 1.f - giou;
    }

    // ---- block reduction (wave=64) ----
    float sb = l1sum, sg = giou_term;
#pragma unroll
    for (int off = 32; off > 0; off >>= 1) {
        sb += __shfl_down(sb, off);
        sg += __shfl_down(sg, off);
    }
    const int wave = tid >> 6, lane = tid & 63;
    if (lane == 0) { red[wave] = sb; red[4 + wave] = sg; }
    __syncthreads();
    if (tid == 0) {
        float a = red[0] + red[1] + red[2] + red[3];
        float g = red[4] + red[5] + red[6] + red[7];
        partials[2 * (size_t)blockIdx.x]     = a;
        partials[2 * (size_t)blockIdx.x + 1] = g;
    }
}

// Deterministic final reduction of per-block partials + 1/af scaling.
__global__ __launch_bounds__(256) void box_loss_final(
    const float* __restrict__ partials, int nblk,
    const int* __restrict__ avg_factor, float* __restrict__ out)
{
    __shared__ float red[8];
    float a = 0.f, g = 0.f;
    for (int i = threadIdx.x; i < nblk; i += 256) {
        a += partials[2 * (size_t)i];
        g += partials[2 * (size_t)i + 1];
    }
#pragma unroll
    for (int off = 32; off > 0; off >>= 1) {
        a += __shfl_down(a, off);
        g += __shfl_down(g, off);
    }
    const int wave = threadIdx.x >> 6, lane = threadIdx.x & 63;
    if (lane == 0) { red[wave] = a; red[4 + wave] = g; }
    __syncthreads();
    if (threadIdx.x == 0) {
        float af = (float)(*avg_factor);
        if (af < 1.f) af = 1.f;
        out[0] = (red[0] + red[1] + red[2] + red[3]) / af;
        out[1] = (red[4] + red[5] + red[6] + red[7]) / af;
    }
}

extern "C" void kernel_launch(void* const* d_in, const int* in_sizes, int n_in,
                              void* d_out, int out_size, void* d_ws, size_t ws_size,
                              hipStream_t stream) {
    const float* box = (const float*)d_in[0];
    const float* tgt = (const float*)d_in[1];
    const float* wgt = (const float*)d_in[2];
    const int*   af  = (const int*)d_in[3];
    float* out = (float*)d_out;
    float* partials = (float*)d_ws;

    int n = in_sizes[0] / 11;
    int nblk = (n + BLOCK - 1) / BLOCK;
    if (nblk < 1) nblk = 1;

    hipLaunchKernelGGL(box_loss_main, dim3(nblk), dim3(BLOCK), 0, stream,
                       box, tgt, wgt, n, partials);
    hipLaunchKernelGGL(box_loss_final, dim3(1), dim3(256), 0, stream,
                       partials, nblk, af, out);
}